// Round 1
// baseline (392.378 us; speedup 1.0000x reference)
//
#include <hip/hip_runtime.h>

#define THREADS 256
#define BLOCKS  2048

__global__ void zero_ws_kernel(float* ws) {
    ws[0] = 0.0f;
}

__global__ __launch_bounds__(THREADS) void edge_loss_kernel(
        const float* __restrict__ V,     // [N,3] f32
        const int*   __restrict__ E,     // [M,2] int32
        const float* __restrict__ rest,  // [M]   f32
        float* __restrict__ ws,          // accumulator (sum of t^2)
        int M) {
    int gid    = blockIdx.x * blockDim.x + threadIdx.x;
    int stride = gridDim.x * blockDim.x;

    float acc = 0.0f;
    for (int i = gid; i < M; i += stride) {
        int2 e = reinterpret_cast<const int2*>(E)[i];
        const float* pa = V + 3l * (long)e.x;
        const float* pb = V + 3l * (long)e.y;
        float dx = pa[0] - pb[0];
        float dy = pa[1] - pb[1];
        float dz = pa[2] - pb[2];
        float len = sqrtf(dx * dx + dy * dy + dz * dz + 1e-12f);
        float t = len - rest[i];
        acc += t * t;
    }

    // wave-64 butterfly reduce
    #pragma unroll
    for (int off = 32; off > 0; off >>= 1)
        acc += __shfl_down(acc, off, 64);

    __shared__ float wsum[THREADS / 64];
    int lane = threadIdx.x & 63;
    int wid  = threadIdx.x >> 6;
    if (lane == 0) wsum[wid] = acc;
    __syncthreads();

    if (threadIdx.x == 0) {
        float s = 0.0f;
        #pragma unroll
        for (int w = 0; w < THREADS / 64; ++w) s += wsum[w];
        atomicAdd(ws, s);
    }
}

__global__ void finalize_kernel(const float* ws, const float* rig2, float* out) {
    out[0] = 0.5f * rig2[0] * ws[0];
}

extern "C" void kernel_launch(void* const* d_in, const int* in_sizes, int n_in,
                              void* d_out, int out_size, void* d_ws, size_t ws_size,
                              hipStream_t stream) {
    const float* V    = (const float*)d_in[0];   // [N,3]
    const int*   E    = (const int*)d_in[1];     // [M,2] flat
    const float* rest = (const float*)d_in[2];   // [M]
    const float* rig2 = (const float*)d_in[3];   // scalar
    // d_in[4] = src_param_id, unused per reference

    int M = in_sizes[2];                         // 12,000,000 edges
    float* ws  = (float*)d_ws;
    float* out = (float*)d_out;

    zero_ws_kernel<<<1, 1, 0, stream>>>(ws);
    edge_loss_kernel<<<BLOCKS, THREADS, 0, stream>>>(V, E, rest, ws, M);
    finalize_kernel<<<1, 1, 0, stream>>>(ws, rig2, out);
}

// Round 3
// 385.163 us; speedup vs baseline: 1.0187x; 1.0187x over previous
//
#include <hip/hip_runtime.h>

#define THREADS 256
#define BATCH   8

__global__ void zero_ws_kernel(float* ws) {
    ws[0] = 0.0f;
}

__global__ __launch_bounds__(THREADS) void edge_loss_kernel(
        const float*     __restrict__ V,     // [N,3] f32
        const long long* __restrict__ E,     // [M] packed (int lo = src, int hi = dst)
        const float*     __restrict__ rest,  // [M] f32
        float* __restrict__ ws,              // accumulator (sum of t^2)
        int M, int T) {                      // T = total threads
    int t = blockIdx.x * THREADS + threadIdx.x;

    long long e[BATCH];
    float r[BATCH];
    float ax[BATCH], ay[BATCH], az[BATCH];
    float bx[BATCH], by[BATCH], bz[BATCH];

    // Phase 1: issue all stream loads (non-temporal: don't evict V from L2)
    #pragma unroll
    for (int k = 0; k < BATCH; ++k) {
        int idx = t + k * T;
        if (idx < M) {
            e[k] = __builtin_nontemporal_load(&E[idx]);
            r[k] = __builtin_nontemporal_load(&rest[idx]);
        } else {
            e[k] = 0;
            r[k] = 0.0f;
        }
    }

    // Phase 2: issue all gather loads (want these cached in L2/L3)
    #pragma unroll
    for (int k = 0; k < BATCH; ++k) {
        int idx = t + k * T;
        if (idx < M) {
            int ia = (int)(e[k] & 0xffffffffll);
            int ib = (int)(e[k] >> 32);
            const float* pa = V + 3 * (size_t)ia;
            const float* pb = V + 3 * (size_t)ib;
            ax[k] = pa[0]; ay[k] = pa[1]; az[k] = pa[2];
            bx[k] = pb[0]; by[k] = pb[1]; bz[k] = pb[2];
        } else {
            ax[k] = ay[k] = az[k] = 0.0f;
            bx[k] = by[k] = bz[k] = 0.0f;
        }
    }

    // Phase 3: compute
    float acc = 0.0f;
    #pragma unroll
    for (int k = 0; k < BATCH; ++k) {
        int idx = t + k * T;
        if (idx < M) {
            float dx = ax[k] - bx[k];
            float dy = ay[k] - by[k];
            float dz = az[k] - bz[k];
            float len = sqrtf(dx * dx + dy * dy + dz * dz + 1e-12f);
            float tt = len - r[k];
            acc += tt * tt;
        }
    }

    // wave-64 butterfly reduce
    #pragma unroll
    for (int off = 32; off > 0; off >>= 1)
        acc += __shfl_down(acc, off, 64);

    __shared__ float wsum[THREADS / 64];
    int lane = threadIdx.x & 63;
    int wid  = threadIdx.x >> 6;
    if (lane == 0) wsum[wid] = acc;
    __syncthreads();

    if (threadIdx.x == 0) {
        float s = 0.0f;
        #pragma unroll
        for (int w = 0; w < THREADS / 64; ++w) s += wsum[w];
        atomicAdd(ws, s);
    }
}

__global__ void finalize_kernel(const float* ws, const float* rig2, float* out) {
    out[0] = 0.5f * rig2[0] * ws[0];
}

extern "C" void kernel_launch(void* const* d_in, const int* in_sizes, int n_in,
                              void* d_out, int out_size, void* d_ws, size_t ws_size,
                              hipStream_t stream) {
    const float*     V    = (const float*)d_in[0];     // [N,3]
    const long long* E    = (const long long*)d_in[1]; // [M,2] packed
    const float*     rest = (const float*)d_in[2];     // [M]
    const float*     rig2 = (const float*)d_in[3];     // scalar

    int M = in_sizes[2];                               // 12,000,000 edges
    int blocks = (M + THREADS * BATCH - 1) / (THREADS * BATCH);
    int T = blocks * THREADS;

    float* ws  = (float*)d_ws;
    float* out = (float*)d_out;

    zero_ws_kernel<<<1, 1, 0, stream>>>(ws);
    edge_loss_kernel<<<blocks, THREADS, 0, stream>>>(V, E, rest, ws, M, T);
    finalize_kernel<<<1, 1, 0, stream>>>(ws, rig2, out);
}

// Round 4
// 383.657 us; speedup vs baseline: 1.0227x; 1.0039x over previous
//
#include <hip/hip_runtime.h>

#define THREADS 256
#define BATCH   8

__global__ void zero_ws_kernel(float* ws) {
    ws[0] = 0.0f;
}

__device__ __forceinline__ void loadV3(const float* __restrict__ V, int i, int N,
                                       float& x, float& y, float& z) {
    if (i + 1 < N) {
        // 16B load (dword-aligned). Covers x,y,z + 1 spill dword.
        float v[4];
        __builtin_memcpy(v, V + 3 * (size_t)i, 16);
        x = v[0]; y = v[1]; z = v[2];
    } else {
        const float* p = V + 3 * (size_t)i;
        x = p[0]; y = p[1]; z = p[2];
    }
}

__global__ __launch_bounds__(THREADS) void edge_loss_kernel(
        const float*     __restrict__ V,     // [N,3] f32
        const long long* __restrict__ E,     // [M] packed (lo = src, hi = dst)
        const float*     __restrict__ rest,  // [M] f32
        float* __restrict__ ws,              // accumulator (sum of t^2)
        int M, int T, int N) {
    int t = blockIdx.x * THREADS + threadIdx.x;

    long long e[BATCH];
    float r[BATCH];
    float ax[BATCH], ay[BATCH], az[BATCH];
    float bx[BATCH], by[BATCH], bz[BATCH];

    // Phase 1: stream loads (non-temporal: don't evict V from L2)
    #pragma unroll
    for (int k = 0; k < BATCH; ++k) {
        int idx = t + k * T;
        if (idx < M) {
            e[k] = __builtin_nontemporal_load(&E[idx]);
            r[k] = __builtin_nontemporal_load(&rest[idx]);
        } else {
            e[k] = 0;
            r[k] = 0.0f;
        }
    }

    // Phase 2: gathers — ONE dwordx4 per endpoint instead of 3 dwords
    #pragma unroll
    for (int k = 0; k < BATCH; ++k) {
        int idx = t + k * T;
        if (idx < M) {
            int ia = (int)(e[k] & 0xffffffffll);
            int ib = (int)(e[k] >> 32);
            loadV3(V, ia, N, ax[k], ay[k], az[k]);
            loadV3(V, ib, N, bx[k], by[k], bz[k]);
        } else {
            ax[k] = ay[k] = az[k] = 0.0f;
            bx[k] = by[k] = bz[k] = 0.0f;
        }
    }

    // Phase 3: compute
    float acc = 0.0f;
    #pragma unroll
    for (int k = 0; k < BATCH; ++k) {
        int idx = t + k * T;
        if (idx < M) {
            float dx = ax[k] - bx[k];
            float dy = ay[k] - by[k];
            float dz = az[k] - bz[k];
            float len = sqrtf(dx * dx + dy * dy + dz * dz + 1e-12f);
            float tt = len - r[k];
            acc += tt * tt;
        }
    }

    // wave-64 butterfly reduce
    #pragma unroll
    for (int off = 32; off > 0; off >>= 1)
        acc += __shfl_down(acc, off, 64);

    __shared__ float wsum[THREADS / 64];
    int lane = threadIdx.x & 63;
    int wid  = threadIdx.x >> 6;
    if (lane == 0) wsum[wid] = acc;
    __syncthreads();

    if (threadIdx.x == 0) {
        float s = 0.0f;
        #pragma unroll
        for (int w = 0; w < THREADS / 64; ++w) s += wsum[w];
        atomicAdd(ws, s);
    }
}

__global__ void finalize_kernel(const float* ws, const float* rig2, float* out) {
    out[0] = 0.5f * rig2[0] * ws[0];
}

extern "C" void kernel_launch(void* const* d_in, const int* in_sizes, int n_in,
                              void* d_out, int out_size, void* d_ws, size_t ws_size,
                              hipStream_t stream) {
    const float*     V    = (const float*)d_in[0];     // [N,3]
    const long long* E    = (const long long*)d_in[1]; // [M,2] packed
    const float*     rest = (const float*)d_in[2];     // [M]
    const float*     rig2 = (const float*)d_in[3];     // scalar

    int N = in_sizes[0] / 3;                           // 2,000,000 nodes
    int M = in_sizes[2];                               // 12,000,000 edges
    int blocks = (M + THREADS * BATCH - 1) / (THREADS * BATCH);
    int T = blocks * THREADS;

    float* ws  = (float*)d_ws;
    float* out = (float*)d_out;

    zero_ws_kernel<<<1, 1, 0, stream>>>(ws);
    edge_loss_kernel<<<blocks, THREADS, 0, stream>>>(V, E, rest, ws, M, T, N);
    finalize_kernel<<<1, 1, 0, stream>>>(ws, rig2, out);
}